// Round 4
// baseline (22.143 us; speedup 1.0000x reference)
//
#include <hip/hip_runtime.h>
#include <cstdint>
#include <cstddef>

// Problem constants (from reference)
#define NAGT 256
#define TT   100
#define NPTS (NAGT * TT)   // 25600
#define PU   10
#define PV   20
#define NS   (PU * PV)     // 200
#define MH   2048
#define MW   2048

// Compile-time linspace tables, bit-identical to numpy linspace(-0.5,0.5,n)
// cast to f32: (float)((double)i * (1/(n-1)) - 0.5), endpoint forced to 0.5f.
#define LUE(i, invn) ((float)((double)(i) * (invn) - 0.5))
__device__ __constant__ float LUT_U[PU] = {
    LUE(0, 1.0/9.0), LUE(1, 1.0/9.0), LUE(2, 1.0/9.0), LUE(3, 1.0/9.0),
    LUE(4, 1.0/9.0), LUE(5, 1.0/9.0), LUE(6, 1.0/9.0), LUE(7, 1.0/9.0),
    LUE(8, 1.0/9.0), 0.5f
};
__device__ __constant__ float LUT_V[PV] = {
    LUE(0,  1.0/19.0), LUE(1,  1.0/19.0), LUE(2,  1.0/19.0), LUE(3,  1.0/19.0),
    LUE(4,  1.0/19.0), LUE(5,  1.0/19.0), LUE(6,  1.0/19.0), LUE(7,  1.0/19.0),
    LUE(8,  1.0/19.0), LUE(9,  1.0/19.0), LUE(10, 1.0/19.0), LUE(11, 1.0/19.0),
    LUE(12, 1.0/19.0), LUE(13, 1.0/19.0), LUE(14, 1.0/19.0), LUE(15, 1.0/19.0),
    LUE(16, 1.0/19.0), LUE(17, 1.0/19.0), LUE(18, 1.0/19.0), 0.5f
};

// Sample geometry, exact reference op order (no contraction, no re-association:
// a 1-ulp change in px near an ix boundary flips collision bits -> O(1) error).
__device__ __forceinline__ void sample_geom(
    int k, float Lv, float Wv, float h0n, float h1n, float cx, float cy,
    float& ox, float& oy, float& px, float& py)
{
    const int iu = k / PV;
    const int iv = k - iu * PV;
    const float bu = __fmul_rn(LUT_U[iu], Lv);
    const float bv = __fmul_rn(LUT_V[iv], Wv);
    ox = __fsub_rn(__fmul_rn(bu, h0n), __fmul_rn(bv, h1n));
    oy = __fadd_rn(__fmul_rn(bu, h1n), __fmul_rn(bv, h0n));
    px = __fadd_rn(cx, ox);
    py = __fadd_rn(cy, oy);
}

template<bool POW2>
__device__ __forceinline__ void point_body(
    int wid, int lane,
    const float* __restrict__ traj,
    const float* __restrict__ veh_att,
    const float* __restrict__ raster,
    const int*   __restrict__ mapixes,
    float dxv, float inv_dx,
    float* __restrict__ out)
{
    // wave-uniform point index -> scalar loads
    const int ws = __builtin_amdgcn_readfirstlane(wid);
    const int a  = ws / TT;

    const float cx = traj[ws * 4 + 0];
    const float cy = traj[ws * 4 + 1];
    const float h0 = traj[ws * 4 + 2];
    const float h1 = traj[ws * 4 + 3];
    const float Lv = veh_att[a * 2 + 0];
    const float Wv = veh_att[a * 2 + 1];
    const int   mp = mapixes[a];

    // h / (||h|| + 1e-8), exact reference op order
    const float nrm = __fsqrt_rn(__fadd_rn(__fmul_rn(h0, h0), __fmul_rn(h1, h1)));
    const float den = __fadd_rn(nrm, 1e-8f);
    const float h0n = __fdiv_rn(h0, den);
    const float h1n = __fdiv_rn(h1, den);

    const float* __restrict__ rb = raster + (size_t)mp * ((size_t)MH * MW);

    const uint32_t SENT = 0xFFFFFFFFu;  // never produced by real d2 (sign bit 0)
    uint32_t d2b[4];                    // per-iteration d2 bits (or sentinel)
    uint32_t mymin = SENT;

    // iterations 0..2 always in range (k = lane + it*64 <= 191 < 200);
    // iteration 3 valid only for lane < 8.
    #pragma unroll
    for (int it = 0; it < 4; ++it) {
        const int k = lane + it * 64;
        const bool active = (it < 3) | (lane < 8);
        d2b[it] = SENT;
        if (active) {
            float ox, oy, px, py;
            sample_geom(k, Lv, Wv, h0n, h1n, cx, cy, ox, oy, px, py);
            const float qx = POW2 ? __fmul_rn(px, inv_dx) : __fdiv_rn(px, dxv);
            const float qy = POW2 ? __fmul_rn(py, inv_dx) : __fdiv_rn(py, dxv);
            int ix = __float2int_rd(qx);
            int iy = __float2int_rd(qy);
            ix = min(max(ix, 0), MW - 1);
            iy = min(max(iy, 0), MH - 1);
            const float val = rb[(iy << 11) | ix];
            if (val < 0.5f) {
                const float d2 = __fadd_rn(__fmul_rn(ox, ox), __fmul_rn(oy, oy));
                d2b[it] = __float_as_uint(d2);
            }
        }
        mymin = min(mymin, d2b[it]);
    }

    // wave-wide u32 min reduce (order-preserving for non-negative floats)
    uint32_t m = mymin;
    #pragma unroll
    for (int off = 32; off > 0; off >>= 1) {
        const uint32_t o = (uint32_t)__shfl_xor((int)m, off, 64);
        m = min(m, o);
    }

    // lowest lane holding the min writes the result
    const unsigned long long holders = __ballot(mymin == m && m != SENT);
    const bool any = (holders != 0ULL);
    const int winner = any ? (__ffsll((long long)holders) - 1) : -1;

    if (any ? (lane == winner) : (lane == 0)) {
        float result = 0.0f;
        if (any) {
            // my lowest iteration matching the min
            int it_sel = 3;
            if (d2b[2] == m) it_sel = 2;
            if (d2b[1] == m) it_sel = 1;
            if (d2b[0] == m) it_sel = 0;
            const int k = lane + it_sel * 64;
            float ox, oy, px, py;
            sample_geom(k, Lv, Wv, h0n, h1n, cx, cy, ox, oy, px, py);
            const float ddx = __fsub_rn(cx, px);  // diff = ctr - cp (reference)
            const float ddy = __fsub_rn(cy, py);
            const float dist = __fsqrt_rn(__fadd_rn(__fmul_rn(ddx, ddx),
                                                    __fmul_rn(ddy, ddy)));
            const float pl  = __fdiv_rn(__fmul_rn(Lv, Lv), 4.0f);
            const float pw  = __fdiv_rn(__fmul_rn(Wv, Wv), 4.0f);
            const float pen = __fsqrt_rn(__fadd_rn(pl, pw));
            result = __fsub_rn(1.0f, __fdiv_rn(dist, pen));
        }
        out[wid] = result;
    }
}

__global__ __launch_bounds__(256) void envcoll_kernel(
    const float* __restrict__ traj,     // [NPTS,4]
    const float* __restrict__ veh_att,  // [NAGT,2]
    const float* __restrict__ raster,   // [4,MH,MW]
    const int*   __restrict__ mapixes,  // [NAGT]
    const float* __restrict__ dxp,      // [1]
    float*       __restrict__ out)      // [NPTS]
{
    const int gtid = blockIdx.x * blockDim.x + threadIdx.x;
    const int wid  = gtid >> 6;
    const int lane = threadIdx.x & 63;
    if (wid >= NPTS) return;

    const float dxv = dxp[0];
    const unsigned int u = __float_as_uint(dxv);
    const unsigned int ex = (u >> 23) & 0xffu;
    const bool pow2 = ((u & 0x007fffffu) == 0u) && ex != 0u && ex != 255u
                      && dxv > 0.0f;
    // exact for pow2 dx: 1/dx and x*(1/dx) are pure exponent shifts
    const float inv_dx = __fdiv_rn(1.0f, dxv);

    if (pow2) {
        point_body<true >(wid, lane, traj, veh_att, raster, mapixes, dxv, inv_dx, out);
    } else {
        point_body<false>(wid, lane, traj, veh_att, raster, mapixes, dxv, inv_dx, out);
    }
}

extern "C" void kernel_launch(void* const* d_in, const int* in_sizes, int n_in,
                              void* d_out, int out_size, void* d_ws, size_t ws_size,
                              hipStream_t stream) {
    const float* traj    = (const float*)d_in[0];
    const float* veh_att = (const float*)d_in[1];
    const float* raster  = (const float*)d_in[2];
    const int*   mapixes = (const int*)d_in[3];
    const float* dxp     = (const float*)d_in[4];
    float* out = (float*)d_out;

    const int block = 256;
    const int grid  = (NPTS * 64) / block;   // 6400
    hipLaunchKernelGGL(envcoll_kernel, dim3(grid), dim3(block), 0, stream,
                       traj, veh_att, raster, mapixes, dxp, out);
}